// Round 14
// baseline (267.257 us; speedup 1.0000x reference)
//
#include <hip/hip_runtime.h>
#include <math.h>

// Problem constants (fixed by reference)
#define B_TOT   256
#define N_TOT   2304
#define IN_DIM  8
#define NC      10      // NUM_CLASSES
#define OD      16      // OUT_DIM
#define CD      160     // NC*OD
#define RBIAS   0.1f

// Tiling: wave-per-class layout. Block = 10 waves (c=0..9) × 64 lanes (b).
#define BTILE    64                      // b per block (= wave lanes)
#define NS       192                     // n-slices (grid.y); grid = 4*192 = 768 = 3 blk/CU
#define NPB      (N_TOT / NS)            // 12 n per block
#define WCH      4                       // W rows staged per chunk (3 chunks)
#define NTHREADS 640                     // 10 waves
#define XR       (NPB * IN_DIM + 4)      // 100: x row stride (measured 0 conflicts)
#define LB       72                      // logit board row stride
#define NF4      (B_TOT * CD / 4)        // 10240 float4 per partial slab
#define RCOLS    32                      // float4-columns per reduce block
#define RGRPS    8                       // y-groups per reduce block
#define RYPER    (NS / RGRPS)            // 24 slabs per (col, grp) thread

// Routing round with LDS-BROADCAST W (R13 post-mortem: scalar-W is K$/L2
// latency-bound and SGPR budget forbids wider pipelining; R14: all 64 lanes
// of wave c read the SAME 16 W floats per (n,i) -> same-address ds_read_b128
// broadcast, conflict-free, ~120cyc pipelined vs ~500cyc scalar chains).
// W staged in 3 chunks of 4 rows (20.5 KB buffer) to keep LDS <= 52 KB ->
// 3 blocks/CU (R13: occupancy loss hurts). x tile in LDS as R12.
// FIRST=1: cw uniform -> acc += u; no logit barriers; 0.1 folded in reduce.
template <int FIRST>
__global__ __launch_bounds__(NTHREADS) void routing_round(
    const float* __restrict__ x,      // [B, N, 8]
    const float* __restrict__ W,      // [N, 8, 160]
    const float* __restrict__ S_acc,  // [B, 160]
    float* __restrict__ part)         // [NS, B, 160]
{
    __shared__ float sh_x[BTILE * XR];            // 25.6 KB
    __shared__ float4 sh_w[WCH * 320];            // 20.5 KB (4 W rows, row-major)
    __shared__ float sh_lg[2][NC * LB];           // 5.8 KB   -> 51.9 KB total

    const int tid = threadIdx.x;
    const int b0  = blockIdx.x * BTILE;
    const int n0  = blockIdx.y * NPB;
    const int b   = tid & 63;
    const int cu  = __builtin_amdgcn_readfirstlane(tid >> 6);

    // ---- stage x tile: [64 b][96 floats], coalesced float4
    {
        const int XT4 = BTILE * (NPB * IN_DIM / 4);   // 1536
        for (int k = tid; k < XT4; k += NTHREADS) {
            int bb   = k / (NPB * 2);
            int off4 = k - bb * (NPB * 2);
            float4 v = *(const float4*)(x + ((size_t)(b0 + bb) * N_TOT + n0) * IN_DIM + off4 * 4);
            *(float4*)(&sh_x[bb * XR + off4 * 4]) = v;
        }
    }

    // ---- S fragment: all 16 d for (b, c)
    float S[OD];
    if (!FIRST) {
        const float4* sp = (const float4*)(S_acc + (size_t)(b0 + b) * CD + cu * OD);
        #pragma unroll
        for (int q = 0; q < 4; q++) ((float4*)S)[q] = sp[q];
    }

    float acc[OD];
    #pragma unroll
    for (int d = 0; d < OD; d++) acc[d] = 0.f;

    const float4* W4 = (const float4*)(W + (size_t)n0 * (IN_DIM * CD));  // 320 f4/row

    for (int h = 0; h < NPB / WCH; h++) {
        __syncthreads();   // WAR: prior chunk's reads done (also covers sh_x on h=0)

        // ---- stage W chunk: rows 4h..4h+3 (1280 float4), coalesced, 2/thread
        #pragma unroll
        for (int k = 0; k < (WCH * 320) / NTHREADS; k++) {
            int j = tid + k * NTHREADS;
            sh_w[j] = W4[(size_t)h * (WCH * 320) + j];
        }
        __syncthreads();   // chunk visible

        for (int nl = 0; nl < WCH; nl++) {
            const int nn = h * WCH + nl;

            float xf[IN_DIM];
            {
                const float4* xp = (const float4*)(&sh_x[b * XR + nn * IN_DIM]);
                ((float4*)xf)[0] = xp[0];
                ((float4*)xf)[1] = xp[1];
            }

            // u[16] from LDS-broadcast W: per i one 64-B row slice, all lanes
            // same address (wave-uniform cu) -> conflict-free broadcast.
            float u[OD];
            {
                const float4* wp = &sh_w[nl * 320 + cu * 4];
                float4 w0 = wp[0], w1 = wp[1], w2 = wp[2], w3 = wp[3];
                float xv = xf[0];
                u[0]=xv*w0.x; u[1]=xv*w0.y; u[2]=xv*w0.z; u[3]=xv*w0.w;
                u[4]=xv*w1.x; u[5]=xv*w1.y; u[6]=xv*w1.z; u[7]=xv*w1.w;
                u[8]=xv*w2.x; u[9]=xv*w2.y; u[10]=xv*w2.z; u[11]=xv*w2.w;
                u[12]=xv*w3.x; u[13]=xv*w3.y; u[14]=xv*w3.z; u[15]=xv*w3.w;
            }
            #pragma unroll
            for (int i = 1; i < IN_DIM; i++) {
                const float4* wp = &sh_w[nl * 320 + i * 40 + cu * 4];
                float4 w0 = wp[0], w1 = wp[1], w2 = wp[2], w3 = wp[3];
                float xv = xf[i];
                u[0]=fmaf(xv,w0.x,u[0]);  u[1]=fmaf(xv,w0.y,u[1]);
                u[2]=fmaf(xv,w0.z,u[2]);  u[3]=fmaf(xv,w0.w,u[3]);
                u[4]=fmaf(xv,w1.x,u[4]);  u[5]=fmaf(xv,w1.y,u[5]);
                u[6]=fmaf(xv,w1.z,u[6]);  u[7]=fmaf(xv,w1.w,u[7]);
                u[8]=fmaf(xv,w2.x,u[8]);  u[9]=fmaf(xv,w2.y,u[9]);
                u[10]=fmaf(xv,w2.z,u[10]); u[11]=fmaf(xv,w2.w,u[11]);
                u[12]=fmaf(xv,w3.x,u[12]); u[13]=fmaf(xv,w3.y,u[13]);
                u[14]=fmaf(xv,w3.z,u[14]); u[15]=fmaf(xv,w3.w,u[15]);
            }

            if (!FIRST) {
                const int cur = nn & 1;
                float lg = 0.f;
                #pragma unroll
                for (int d = 0; d < OD; d++) lg = fmaf(u[d], S[d], lg);
                sh_lg[cur][cu * LB + b] = lg;
                __syncthreads();

                float m = -1e30f, row[NC];
                #pragma unroll
                for (int k = 0; k < NC; k++) {
                    row[k] = sh_lg[cur][k * LB + b];
                    m = fmaxf(m, row[k]);
                }
                float den = 0.f;
                #pragma unroll
                for (int k = 0; k < NC; k++) den += __expf(row[k] - m);
                float cw = __expf(lg - m) / den;

                #pragma unroll
                for (int d = 0; d < OD; d++) acc[d] = fmaf(cw, u[d], acc[d]);
            } else {
                #pragma unroll
                for (int d = 0; d < OD; d++) acc[d] += u[d];
            }
        }
    }

    float* dst = part + ((size_t)blockIdx.y * B_TOT + (b0 + b)) * CD + cu * OD;
    #pragma unroll
    for (int q = 0; q < 4; q++)
        ((float4*)dst)[q] = ((float4*)acc)[q];
}

// ===== Full-device merged reduce (R12, proven ~7us): 320 blocks × 256 threads.
__global__ __launch_bounds__(256) void reduce_round(
    const float* __restrict__ part,   // [NS, B, 160]
    float* __restrict__ S_acc,        // [B, 160]
    float* __restrict__ v_out,        // [B, 10, 16]
    float scale, int round)
{
    __shared__ float4 sh[RGRPS][RCOLS];   // 4 KB

    const int col = threadIdx.x & (RCOLS - 1);
    const int grp = threadIdx.x >> 5;               // 0..7
    const int g   = blockIdx.x * RCOLS + col;       // float4 column index

    const float4* p4 = (const float4*)part + (size_t)grp * NF4 + g;
    float4 s = { 0.f, 0.f, 0.f, 0.f };
    #pragma unroll 4
    for (int y = 0; y < RYPER; y++) {               // slabs grp, grp+8, ...
        float4 t = p4[(size_t)y * RGRPS * NF4];
        s.x += t.x; s.y += t.y; s.z += t.z; s.w += t.w;
    }
    sh[grp][col] = s;
    __syncthreads();

    if (threadIdx.x < RCOLS) {
        float4 t = { 0.f, 0.f, 0.f, 0.f };
        #pragma unroll
        for (int k = 0; k < RGRPS; k++) {
            float4 q = sh[k][col];
            t.x += q.x; t.y += q.y; t.z += q.z; t.w += q.w;
        }
        t.x = t.x * scale + RBIAS;
        t.y = t.y * scale + RBIAS;
        t.z = t.z * scale + RBIAS;
        t.w = t.w * scale + RBIAS;

        if (round == 0) {
            ((float4*)S_acc)[g] = t;          // store — no memset required
        } else if (round == 1) {
            float4 o = ((float4*)S_acc)[g];
            o.x += t.x; o.y += t.y; o.z += t.z; o.w += t.w;
            ((float4*)S_acc)[g] = o;
        } else {
            // squash: 16 d = 4 consecutive float4 columns = lanes 4k..4k+3
            float ss = t.x * t.x + t.y * t.y + t.z * t.z + t.w * t.w;
            ss += __shfl_xor(ss, 1, 64);
            ss += __shfl_xor(ss, 2, 64);
            float norm = sqrtf(ss);
            float k2 = norm / (1.0f + ss);
            float4 v = { t.x * k2, t.y * k2, t.z * k2, t.w * k2 };
            ((float4*)v_out)[g] = v;
        }
    }
}

extern "C" void kernel_launch(void* const* d_in, const int* in_sizes, int n_in,
                              void* d_out, int out_size, void* d_ws, size_t ws_size,
                              hipStream_t stream) {
    const float* x = (const float*)d_in[0];   // [256,2304,8]
    const float* W = (const float*)d_in[1];   // [2304,8,160]
    float* out = (float*)d_out;               // [256,10,16]

    // Workspace (every byte written before read each call — re-poison safe)
    float* part  = (float*)d_ws;                            // NS * 40960  (~31.5 MB)
    float* S_acc = part + (size_t)NS * B_TOT * CD;          // 40960 floats

    const dim3 rgrid(B_TOT / BTILE, NS);
    const int  RG = NF4 / RCOLS;   // 320 reduce blocks — spans the device

    // Round 0 (uniform cw; 0.1 folded into reduce scale; S_acc stored not added)
    routing_round<1><<<rgrid, NTHREADS, 0, stream>>>(x, W, S_acc, part);
    reduce_round<<<RG, 256, 0, stream>>>(part, S_acc, out, 0.1f, 0);

    // Round 1
    routing_round<0><<<rgrid, NTHREADS, 0, stream>>>(x, W, S_acc, part);
    reduce_round<<<RG, 256, 0, stream>>>(part, S_acc, out, 1.0f, 1);

    // Round 2 (+final squash fused)
    routing_round<0><<<rgrid, NTHREADS, 0, stream>>>(x, W, S_acc, part);
    reduce_round<<<RG, 256, 0, stream>>>(part, S_acc, out, 1.0f, 2);
}

// Round 15
// 237.413 us; speedup vs baseline: 1.1257x; 1.1257x over previous
//
#include <hip/hip_runtime.h>
#include <hip/hip_fp16.h>
#include <math.h>

// Problem constants (fixed by reference)
#define B_TOT   256
#define N_TOT   2304
#define IN_DIM  8
#define NC      10      // NUM_CLASSES
#define OD      16      // OUT_DIM
#define CD      160     // NC*OD
#define RBIAS   0.1f

// Tiling: wave-per-class layout. Block = 10 waves (c=0..9) × 64 lanes (b).
#define BTILE    64                      // b per block (= wave lanes)
#define NS       192                     // n-slices (grid.y); grid = 4*192 = 768 = 3 blk/CU
#define NPB      (N_TOT / NS)            // 12 n per block
#define NTHREADS 640                     // 10 waves
#define XR       (NPB * IN_DIM + 4)      // 100: x row stride
#define LB       72                      // logit board row stride
#define NF4      (B_TOT * CD / 4)        // 10240 float4 per partial slab
#define RCOLS    32                      // float4-columns per reduce block
#define RGRPS    8                       // y-groups per reduce block
#define RYPER    (NS / RGRPS)            // 24 slabs per (col, grp) thread

// ===== Round 0: R12's proven scalar-W kernel (51.5us) + optional fp16 u_hat
// store. u_hat layout [N][C][B][16] fp16: lane=b -> 32 B/lane contiguous =
// 2 KB/wave coalesced stores (and loads in rounds 1-2). fp16 not bf16:
// 11-bit mantissa keeps s-error ~3e-3 vs 1.6e-2 threshold (bf16 would be ~8x).
template <int STORE>
__global__ __launch_bounds__(NTHREADS) void routing_r0(
    const float* __restrict__ x,      // [B, N, 8]
    const float* __restrict__ W,      // [N, 8, 160]
    float* __restrict__ part,         // [NS, B, 160]
    __half* __restrict__ uh)          // [N, C, B, 16] fp16 cache
{
    __shared__ float sh_x[BTILE * XR];            // 25.6 KB

    const int tid = threadIdx.x;
    const int b0  = blockIdx.x * BTILE;
    const int n0  = blockIdx.y * NPB;
    const int b   = tid & 63;
    const int cu  = __builtin_amdgcn_readfirstlane(tid >> 6);

    // ---- stage x tile: [64 b][96 floats], coalesced float4
    {
        const int XT4 = BTILE * (NPB * IN_DIM / 4);   // 1536
        for (int k = tid; k < XT4; k += NTHREADS) {
            int bb   = k / (NPB * 2);
            int off4 = k - bb * (NPB * 2);
            float4 v = *(const float4*)(x + ((size_t)(b0 + bb) * N_TOT + n0) * IN_DIM + off4 * 4);
            *(float4*)(&sh_x[bb * XR + off4 * 4]) = v;
        }
    }

    float acc[OD];
    #pragma unroll
    for (int d = 0; d < OD; d++) acc[d] = 0.f;

    __syncthreads();   // sh_x ready

    const float* Wc = W + cu * OD;    // wave-uniform base -> scalar loads

    for (int nn = 0; nn < NPB; nn++) {
        float xf[IN_DIM];
        {
            const float4* xp = (const float4*)(&sh_x[b * XR + nn * IN_DIM]);
            ((float4*)xf)[0] = xp[0];
            ((float4*)xf)[1] = xp[1];
        }

        const float* Wn = Wc + (size_t)(n0 + nn) * (IN_DIM * CD);
        float u[OD];
        #pragma unroll
        for (int d = 0; d < OD; d++) u[d] = xf[0] * Wn[d];
        #pragma unroll
        for (int i = 1; i < IN_DIM; i++) {
            const float* Wi = Wn + i * CD;
            #pragma unroll
            for (int d = 0; d < OD; d++) u[d] = fmaf(xf[i], Wi[d], u[d]);
        }

        #pragma unroll
        for (int d = 0; d < OD; d++) acc[d] += u[d];   // cw=1/10 folded in reduce

        if (STORE) {
            __half2 hp[8];
            #pragma unroll
            for (int q = 0; q < 8; q++)
                hp[q] = __floats2half2_rn(u[2 * q], u[2 * q + 1]);
            uint4* dst = (uint4*)(uh + ((size_t)((n0 + nn) * NC + cu) * B_TOT + (b0 + b)) * OD);
            dst[0] = *(uint4*)&hp[0];
            dst[1] = *(uint4*)&hp[4];
        }
    }

    float* dst = part + ((size_t)blockIdx.y * B_TOT + (b0 + b)) * CD + cu * OD;
    #pragma unroll
    for (int q = 0; q < 4; q++)
        ((float4*)dst)[q] = ((float4*)acc)[q];
}

// ===== Rounds 1-2 (cached): no x, no W, no s_loads — stream u_hat fp16.
// Per n: 32 B coalesced load + cvt + logit dot + board softmax + acc.
// Manual 1-deep prefetch to keep 2 loads in flight across the barrier.
__global__ __launch_bounds__(NTHREADS) void routing_cached(
    const __half* __restrict__ uh,    // [N, C, B, 16]
    const float* __restrict__ S_acc,  // [B, 160]
    float* __restrict__ part)         // [NS, B, 160]
{
    __shared__ float sh_lg[2][NC * LB];           // 5.8 KB only

    const int tid = threadIdx.x;
    const int b0  = blockIdx.x * BTILE;
    const int n0  = blockIdx.y * NPB;
    const int b   = tid & 63;
    const int cu  = __builtin_amdgcn_readfirstlane(tid >> 6);

    float S[OD];
    {
        const float4* sp = (const float4*)(S_acc + (size_t)(b0 + b) * CD + cu * OD);
        #pragma unroll
        for (int q = 0; q < 4; q++) ((float4*)S)[q] = sp[q];
    }

    float acc[OD];
    #pragma unroll
    for (int d = 0; d < OD; d++) acc[d] = 0.f;

    const uint4* ub = (const uint4*)(uh + ((size_t)(n0 * NC + cu) * B_TOT + (b0 + b)) * OD);
    const size_t nstride = (size_t)NC * B_TOT * 2;   // uint4 units between n rows

    uint4 p0 = ub[0], p1 = ub[1];    // prefetch n0

    for (int nn = 0; nn < NPB; nn++) {
        uint4 q0, q1;
        if (nn + 1 < NPB) {
            const uint4* nx = ub + (size_t)(nn + 1) * nstride;
            q0 = nx[0]; q1 = nx[1];
        }

        float u[OD];
        #pragma unroll
        for (int j = 0; j < 4; j++) {
            float2 f = __half22float2(((const __half2*)&p0)[j]);
            u[2 * j] = f.x;  u[2 * j + 1] = f.y;
        }
        #pragma unroll
        for (int j = 0; j < 4; j++) {
            float2 f = __half22float2(((const __half2*)&p1)[j]);
            u[8 + 2 * j] = f.x;  u[8 + 2 * j + 1] = f.y;
        }

        const int cur = nn & 1;
        float lg = 0.f;
        #pragma unroll
        for (int d = 0; d < OD; d++) lg = fmaf(u[d], S[d], lg);
        sh_lg[cur][cu * LB + b] = lg;
        __syncthreads();

        float m = -1e30f, row[NC];
        #pragma unroll
        for (int k = 0; k < NC; k++) {
            row[k] = sh_lg[cur][k * LB + b];
            m = fmaxf(m, row[k]);
        }
        float den = 0.f;
        #pragma unroll
        for (int k = 0; k < NC; k++) den += __expf(row[k] - m);
        float cw = __expf(lg - m) / den;

        #pragma unroll
        for (int d = 0; d < OD; d++) acc[d] = fmaf(cw, u[d], acc[d]);

        p0 = q0;  p1 = q1;
    }

    float* dst = part + ((size_t)blockIdx.y * B_TOT + (b0 + b)) * CD + cu * OD;
    #pragma unroll
    for (int q = 0; q < 4; q++)
        ((float4*)dst)[q] = ((float4*)acc)[q];
}

// ===== Fallback rounds 1-2: R12's exact scalar-W kernel (if ws too small).
__global__ __launch_bounds__(NTHREADS) void routing_scalar(
    const float* __restrict__ x, const float* __restrict__ W,
    const float* __restrict__ S_acc, float* __restrict__ part)
{
    __shared__ float sh_x[BTILE * XR];
    __shared__ float sh_lg[2][NC * LB];

    const int tid = threadIdx.x;
    const int b0  = blockIdx.x * BTILE;
    const int n0  = blockIdx.y * NPB;
    const int b   = tid & 63;
    const int cu  = __builtin_amdgcn_readfirstlane(tid >> 6);

    {
        const int XT4 = BTILE * (NPB * IN_DIM / 4);
        for (int k = tid; k < XT4; k += NTHREADS) {
            int bb   = k / (NPB * 2);
            int off4 = k - bb * (NPB * 2);
            float4 v = *(const float4*)(x + ((size_t)(b0 + bb) * N_TOT + n0) * IN_DIM + off4 * 4);
            *(float4*)(&sh_x[bb * XR + off4 * 4]) = v;
        }
    }

    float S[OD];
    {
        const float4* sp = (const float4*)(S_acc + (size_t)(b0 + b) * CD + cu * OD);
        #pragma unroll
        for (int q = 0; q < 4; q++) ((float4*)S)[q] = sp[q];
    }

    float acc[OD];
    #pragma unroll
    for (int d = 0; d < OD; d++) acc[d] = 0.f;

    __syncthreads();

    const float* Wc = W + cu * OD;

    for (int nn = 0; nn < NPB; nn++) {
        float xf[IN_DIM];
        {
            const float4* xp = (const float4*)(&sh_x[b * XR + nn * IN_DIM]);
            ((float4*)xf)[0] = xp[0];
            ((float4*)xf)[1] = xp[1];
        }
        const float* Wn = Wc + (size_t)(n0 + nn) * (IN_DIM * CD);
        float u[OD];
        #pragma unroll
        for (int d = 0; d < OD; d++) u[d] = xf[0] * Wn[d];
        #pragma unroll
        for (int i = 1; i < IN_DIM; i++) {
            const float* Wi = Wn + i * CD;
            #pragma unroll
            for (int d = 0; d < OD; d++) u[d] = fmaf(xf[i], Wi[d], u[d]);
        }
        const int cur = nn & 1;
        float lg = 0.f;
        #pragma unroll
        for (int d = 0; d < OD; d++) lg = fmaf(u[d], S[d], lg);
        sh_lg[cur][cu * LB + b] = lg;
        __syncthreads();
        float m = -1e30f, row[NC];
        #pragma unroll
        for (int k = 0; k < NC; k++) { row[k] = sh_lg[cur][k * LB + b]; m = fmaxf(m, row[k]); }
        float den = 0.f;
        #pragma unroll
        for (int k = 0; k < NC; k++) den += __expf(row[k] - m);
        float cw = __expf(lg - m) / den;
        #pragma unroll
        for (int d = 0; d < OD; d++) acc[d] = fmaf(cw, u[d], acc[d]);
    }

    float* dst = part + ((size_t)blockIdx.y * B_TOT + (b0 + b)) * CD + cu * OD;
    #pragma unroll
    for (int q = 0; q < 4; q++)
        ((float4*)dst)[q] = ((float4*)acc)[q];
}

// ===== Full-device merged reduce (R12, proven): 320 blocks × 256 threads.
__global__ __launch_bounds__(256) void reduce_round(
    const float* __restrict__ part, float* __restrict__ S_acc,
    float* __restrict__ v_out, float scale, int round)
{
    __shared__ float4 sh[RGRPS][RCOLS];

    const int col = threadIdx.x & (RCOLS - 1);
    const int grp = threadIdx.x >> 5;
    const int g   = blockIdx.x * RCOLS + col;

    const float4* p4 = (const float4*)part + (size_t)grp * NF4 + g;
    float4 s = { 0.f, 0.f, 0.f, 0.f };
    #pragma unroll 4
    for (int y = 0; y < RYPER; y++) {
        float4 t = p4[(size_t)y * RGRPS * NF4];
        s.x += t.x; s.y += t.y; s.z += t.z; s.w += t.w;
    }
    sh[grp][col] = s;
    __syncthreads();

    if (threadIdx.x < RCOLS) {
        float4 t = { 0.f, 0.f, 0.f, 0.f };
        #pragma unroll
        for (int k = 0; k < RGRPS; k++) {
            float4 q = sh[k][col];
            t.x += q.x; t.y += q.y; t.z += q.z; t.w += q.w;
        }
        t.x = t.x * scale + RBIAS;
        t.y = t.y * scale + RBIAS;
        t.z = t.z * scale + RBIAS;
        t.w = t.w * scale + RBIAS;

        if (round == 0) {
            ((float4*)S_acc)[g] = t;
        } else if (round == 1) {
            float4 o = ((float4*)S_acc)[g];
            o.x += t.x; o.y += t.y; o.z += t.z; o.w += t.w;
            ((float4*)S_acc)[g] = o;
        } else {
            float ss = t.x * t.x + t.y * t.y + t.z * t.z + t.w * t.w;
            ss += __shfl_xor(ss, 1, 64);
            ss += __shfl_xor(ss, 2, 64);
            float norm = sqrtf(ss);
            float k2 = norm / (1.0f + ss);
            float4 v = { t.x * k2, t.y * k2, t.z * k2, t.w * k2 };
            ((float4*)v_out)[g] = v;
        }
    }
}

extern "C" void kernel_launch(void* const* d_in, const int* in_sizes, int n_in,
                              void* d_out, int out_size, void* d_ws, size_t ws_size,
                              hipStream_t stream) {
    const float* x = (const float*)d_in[0];   // [256,2304,8]
    const float* W = (const float*)d_in[1];   // [2304,8,160]
    float* out = (float*)d_out;               // [256,10,16]

    float* part  = (float*)d_ws;                            // NS * 40960  (~31.5 MB)
    float* S_acc = part + (size_t)NS * B_TOT * CD;          // 40960 floats
    __half* uh   = (__half*)(S_acc + (size_t)B_TOT * CD);   // 188.7 MB fp16 cache

    const size_t need = ((size_t)(NS + 1) * B_TOT * CD) * sizeof(float)
                      + (size_t)N_TOT * NC * B_TOT * OD * sizeof(__half);
    const bool cached = (ws_size >= need);   // deterministic -> graph-safe

    const dim3 rgrid(B_TOT / BTILE, NS);
    const int  RG = NF4 / RCOLS;   // 320 reduce blocks

    if (cached) {
        routing_r0<1><<<rgrid, NTHREADS, 0, stream>>>(x, W, part, uh);
        reduce_round<<<RG, 256, 0, stream>>>(part, S_acc, out, 0.1f, 0);
        routing_cached<<<rgrid, NTHREADS, 0, stream>>>(uh, S_acc, part);
        reduce_round<<<RG, 256, 0, stream>>>(part, S_acc, out, 1.0f, 1);
        routing_cached<<<rgrid, NTHREADS, 0, stream>>>(uh, S_acc, part);
        reduce_round<<<RG, 256, 0, stream>>>(part, S_acc, out, 1.0f, 2);
    } else {
        routing_r0<0><<<rgrid, NTHREADS, 0, stream>>>(x, W, part, nullptr);
        reduce_round<<<RG, 256, 0, stream>>>(part, S_acc, out, 0.1f, 0);
        routing_scalar<<<rgrid, NTHREADS, 0, stream>>>(x, W, S_acc, part);
        reduce_round<<<RG, 256, 0, stream>>>(part, S_acc, out, 1.0f, 1);
        routing_scalar<<<rgrid, NTHREADS, 0, stream>>>(x, W, S_acc, part);
        reduce_round<<<RG, 256, 0, stream>>>(part, S_acc, out, 1.0f, 2);
    }
}